// Round 4
// baseline (422.086 us; speedup 1.0000x reference)
//
#include <hip/hip_runtime.h>
#include <hip/hip_bf16.h>

#define B_   4
#define L_   4096
#define D_   1024
#define DFF_ 4096
#define K_   2048

typedef __attribute__((ext_vector_type(8))) short bf16x8;
typedef __attribute__((ext_vector_type(4))) float f32x4;
typedef unsigned short u16;

__device__ __forceinline__ u16 f2bf(float f) {
    unsigned u = __float_as_uint(f);
    u += 0x7fffu + ((u >> 16) & 1u);          // round-to-nearest-even
    return (u16)(u >> 16);
}

__device__ __forceinline__ float gelu_fast(float v) {
    float z = 1.5957691216057308f * v * (1.0f + 0.044715f * v * v);
    float e = __builtin_amdgcn_exp2f(-1.4426950408889634f * z);
    return v * __builtin_amdgcn_rcpf(1.0f + e);
}

__device__ __forceinline__ void gload_lds16(const void* g, void* l) {
    __builtin_amdgcn_global_load_lds(
        (const __attribute__((address_space(1))) void*)g,
        (__attribute__((address_space(3))) void*)l, 16, 0, 0);
}

// ============ fused prep: score (blocks 0..4095) + W1 transpose (4096..8191)
// ============             + W2 transpose (8192..12287)
__global__ __launch_bounds__(256) void prep_kernel(
    const float* __restrict__ x, const float* __restrict__ wr,
    const float* __restrict__ br, float* __restrict__ scores,
    const float* __restrict__ W1, const float* __restrict__ W2,
    u16* __restrict__ W1T, u16* __restrict__ W2T)
{
    __shared__ float t[32][33];
    const int bb = blockIdx.x;
    if (bb < 4096) {
        // router scores: one wave per token, fp64 accumulate
        int gtid  = bb * 256 + threadIdx.x;
        int token = gtid >> 6;
        int lane  = threadIdx.x & 63;
        const float* xr = x + (size_t)token * D_;
        double acc = 0.0;
        #pragma unroll
        for (int i = 0; i < 4; ++i) {
            int off = (lane + i * 64) * 4;
            float4 xv = *(const float4*)(xr + off);
            float4 wv = *(const float4*)(wr + off);
            acc += (double)xv.x * wv.x + (double)xv.y * wv.y +
                   (double)xv.z * wv.z + (double)xv.w * wv.w;
        }
        #pragma unroll
        for (int off = 32; off > 0; off >>= 1)
            acc += __shfl_down(acc, off);
        if (lane == 0) scores[token] = (float)(acc + (double)br[0]);
        return;
    }
    // transpose + fp32->bf16: out[n][k] = bf16(in[k][n])
    const float* in; u16* outb; int RK, RN, bx, by;
    if (bb < 8192) {
        int i = bb - 4096; in = W1; outb = W1T; RK = D_; RN = DFF_;
        bx = i & 127; by = i >> 7;
    } else {
        int i = bb - 8192; in = W2; outb = W2T; RK = DFF_; RN = D_;
        bx = i & 31; by = i >> 5;
    }
    int n0 = bx * 32, k0 = by * 32;
    int tx = threadIdx.x & 31, ty = threadIdx.x >> 5;
    #pragma unroll
    for (int i = 0; i < 4; ++i)
        t[ty + 8 * i][tx] = in[(size_t)(k0 + ty + 8 * i) * RN + (n0 + tx)];
    __syncthreads();
    #pragma unroll
    for (int i = 0; i < 4; ++i)
        outb[(size_t)(n0 + ty + 8 * i) * RK + (k0 + tx)] = f2bf(t[tx][ty + 8 * i]);
}

// ============ rank (exact top-k, jax tie-break) + zero unselected out rows
__global__ __launch_bounds__(256) void rank_zero_kernel(
    const float* __restrict__ scores, int* __restrict__ sel,
    float* __restrict__ out)
{
    __shared__ float sc[L_];
    __shared__ int selLds[256];
    int b = blockIdx.y;
    int t = threadIdx.x;
    int l = blockIdx.x * 256 + t;
    const float* sb = scores + b * L_;
    for (int i = t; i < L_; i += 256) sc[i] = sb[i];
    __syncthreads();
    float s = sc[l];
    int cnt = 0;
    for (int j = 0; j < L_; ++j) {
        float v = sc[j];
        cnt += (int)((v > s) || (v == s && j < l));
    }
    int issel = (cnt < K_) ? 1 : 0;
    sel[b * L_ + l] = issel;
    selLds[t] = issel;
    __syncthreads();
    float* obase = out + ((size_t)b * L_ + (size_t)blockIdx.x * 256) * D_;
    float4 z = make_float4(0.f, 0.f, 0.f, 0.f);
    for (int j = 0; j < 256; ++j)
        if (!selLds[j])
            *(float4*)(obase + (size_t)j * D_ + t * 4) = z;
}

// ---------------- compact selected indices (ascending) ----------------
__global__ __launch_bounds__(256) void compact_kernel(
    const int* __restrict__ sel, int* __restrict__ idx)
{
    __shared__ int psum[256];
    int b = blockIdx.x, t = threadIdx.x;
    const int* sb = sel + b * L_;
    int base = t * 16;
    int flags[16]; int c = 0;
    #pragma unroll
    for (int i = 0; i < 16; ++i) { flags[i] = sb[base + i]; c += flags[i]; }
    psum[t] = c;
    __syncthreads();
    if (t == 0) {
        int acc = 0;
        for (int j = 0; j < 256; ++j) { int v = psum[j]; psum[j] = acc; acc += v; }
    }
    __syncthreads();
    int p = psum[t];
    #pragma unroll
    for (int i = 0; i < 16; ++i)
        if (flags[i]) idx[b * K_ + (p++)] = base + i;
}

// ---------------- gather selected rows, fp32->bf16 ----------------
__global__ __launch_bounds__(256) void gather_bf16_kernel(
    const float* __restrict__ x, const int* __restrict__ idxg,
    int row0, u16* __restrict__ xsel)
{
    int rl = blockIdx.x;
    int grow = row0 + rl;
    int tok = idxg[grow];
    int bb = grow >> 11;
    const float* src = x + ((size_t)bb * L_ + (size_t)tok) * D_;
    int t = threadIdx.x;
    float4 v = *(const float4*)(src + t * 4);
    ushort4 o;
    o.x = f2bf(v.x); o.y = f2bf(v.y); o.z = f2bf(v.z); o.w = f2bf(v.w);
    *(ushort4*)(xsel + (size_t)rl * D_ + t * 4) = o;
}

// ======================= gemm1: 256x256 8-phase (T3+T4+T5) =======================
// A: xsel [M][1024] bf16.  Bm: W1T [4096][1024] bf16 (n-major).
// h[row][col] = bf16(gelu(acc + b1[col])).  K=1024 -> NT=16 K-tiles, 8 iterations.
#define G1_NT 16

__device__ __forceinline__ void wait_vm4() {
    asm volatile("s_waitcnt vmcnt(4)" ::: "memory");
    __builtin_amdgcn_sched_barrier(0);
}
__device__ __forceinline__ void wait_vm0() {
    asm volatile("s_waitcnt vmcnt(0)" ::: "memory");
    __builtin_amdgcn_sched_barrier(0);
}

__global__ __launch_bounds__(512, 2) void gemm1_8ph_kernel(
    const u16* __restrict__ A, const u16* __restrict__ Bm,
    const float* __restrict__ bias, u16* __restrict__ hout)
{
    // 128 KiB LDS: slots SH[d*2+h] = A(d,h), SH[4+d*2+h] = B(d,h); each [256][32] bf16.
    // Reused after the K-loop as a 256x256 bf16 C-tile for coalesced h writes.
    __shared__ u16 SH[8][8192];

    const int tid  = threadIdx.x;
    const int lane = tid & 63;
    const int wid  = tid >> 6;
    const int wm = wid >> 2, wn = wid & 3;     // 2M x 4N waves
    const int fr = lane & 15;
    const int kq = (lane >> 4) * 8;
    const int rq = (lane >> 4) * 4;

    // XCD-aware swizzle (nwg = 16 * (M/256), always % 8 == 0)
    const int nwg = gridDim.x;
    const int o   = blockIdx.x;
    const int swz = (o & 7) * (nwg >> 3) + (o >> 3);
    const int bn  = (swz & 15) * 256;          // N tile (gx = 4096/256 = 16)
    const int bm  = (swz >> 4) * 256;          // M tile

    // staging thread-invariants: chunk c=tid -> row c>>2, kcol (c&3)*8 ; chunk2 = +512
    const int srow = tid >> 2;
    const int skof = (tid & 3) * 8;
    const u16* Abase = A  + (size_t)(bm + srow) * D_ + skof;
    const u16* Bbase = Bm + (size_t)(bn + srow) * D_ + skof;

    f32x4 acc[8][4];
    #pragma unroll
    for (int m = 0; m < 8; ++m)
        #pragma unroll
        for (int n = 0; n < 4; ++n) acc[m][n] = (f32x4)0.0f;

    // stage half-tile s: kt=s>>2, j=s&3 {0:Ak0,1:Bk0,2:Ak1,3:Bk1}
    auto stage = [&](int s) {
        int kt = s >> 2, j = s & 3;
        int d = kt & 1, h = j >> 1;
        int koff = kt * 64 + h * 32;
        if (j & 1) {
            u16* dst = &SH[4 + d * 2 + h][0] + tid * 8;
            gload_lds16(Bbase + koff, dst);
            gload_lds16(Bbase + koff + (size_t)128 * D_, dst + 4096);
        } else {
            u16* dst = &SH[d * 2 + h][0] + tid * 8;
            gload_lds16(Abase + koff, dst);
            gload_lds16(Abase + koff + (size_t)128 * D_, dst + 4096);
        }
    };

    // prologue: stage halves 0..5 (K-tile0 full + K-tile1 k0-halves)
    #pragma unroll
    for (int s = 0; s < 6; ++s) stage(s);
    wait_vm4();                                // halves 0..3 (kt0) complete
    __builtin_amdgcn_s_barrier();

    bf16x8 bfv[4];
    for (int i = 0; i < G1_NT / 2; ++i) {
        #pragma unroll
        for (int p = 0; p < 8; ++p) {
            const int kt  = 2 * i + (p >> 2);
            const int d   = kt & 1;
            const int kh  = (p >> 1) & 1;
            const int mlo = (p & 1) * 4;
            // ds_reads: B-frags on even sub-phase, A-frags always
            if ((p & 1) == 0) {
                #pragma unroll
                for (int n = 0; n < 4; ++n)
                    bfv[n] = *(const bf16x8*)(&SH[4 + d * 2 + kh][0] +
                              (wn * 64 + n * 16 + fr) * 32 + kq);
            }
            bf16x8 af[4];
            #pragma unroll
            for (int q = 0; q < 4; ++q)
                af[q] = *(const bf16x8*)(&SH[d * 2 + kh][0] +
                          (wm * 128 + (mlo + q) * 16 + fr) * 32 + kq);
            // stage one half-tile, 6 ahead (every overwrite >= 1 barrier after last read)
            int s = 8 * i + p + 6;
            if (s < 4 * G1_NT) stage(s);
            __builtin_amdgcn_s_barrier();
            asm volatile("s_waitcnt lgkmcnt(0)" ::: "memory");
            __builtin_amdgcn_sched_barrier(0);
            __builtin_amdgcn_s_setprio(1);
            #pragma unroll
            for (int q = 0; q < 4; ++q)
                #pragma unroll
                for (int n = 0; n < 4; ++n)
                    acc[mlo + q][n] = __builtin_amdgcn_mfma_f32_16x16x32_bf16(
                        af[q], bfv[n], acc[mlo + q][n], 0, 0, 0);
            __builtin_amdgcn_s_setprio(0);
            // K-tile boundary waits: counted vmcnt, drain 0 only entering last tile
            if (p == 3) {
                if (i == G1_NT / 2 - 1) wait_vm0(); else wait_vm4();
            } else if (p == 7) {
                if (i < G1_NT / 2 - 1) wait_vm4();
            }
            __builtin_amdgcn_s_barrier();
        }
    }

    // ---- epilogue: bias+gelu -> bf16 into LDS C-tile, then coalesced 16B stores ----
    u16* ct = &SH[0][0];                       // [256][256] bf16 = 128 KiB
    #pragma unroll
    for (int n = 0; n < 4; ++n) {
        const int col = wn * 64 + n * 16 + fr;
        const float bc = bias[bn + col];
        #pragma unroll
        for (int m = 0; m < 8; ++m) {
            const int rb = wm * 128 + m * 16 + rq;
            #pragma unroll
            for (int r = 0; r < 4; ++r)
                ct[(rb + r) * 256 + col] = f2bf(gelu_fast(acc[m][n][r] + bc));
        }
    }
    __syncthreads();
    const int row   = tid >> 1;
    const int hhalf = tid & 1;
    const u16* src = ct + row * 256 + hhalf * 128;
    u16* dst = hout + (size_t)(bm + row) * DFF_ + bn + hhalf * 128;
    bf16x8 tmp[16];
    #pragma unroll
    for (int c = 0; c < 16; ++c) {             // XOR order: spread LDS banks
        int cc = c ^ (tid & 15);
        tmp[cc] = *(const bf16x8*)(src + cc * 8);
    }
    #pragma unroll
    for (int c = 0; c < 16; ++c)               // sequential: coalesced 16B stores
        *(bf16x8*)(dst + c * 8) = tmp[c];
}

// ======================= gemm2: proven 128x128 m97 + XCD swizzle =======================
// A: h [M][4096] bf16.  Bm: W2T [1024][4096] bf16.  Scatter-write fp32 out + b2.
__global__ __launch_bounds__(256) void gemm2_kernel(
    const u16* __restrict__ A, const u16* __restrict__ Bm,
    const float* __restrict__ bias, float* __restrict__ outp,
    const int* __restrict__ idxg, int row0)
{
    __shared__ u16 As[128][32];
    __shared__ u16 Bs[128][32];

    const int tid  = threadIdx.x;
    const int lane = tid & 63;
    const int wave = tid >> 6;
    const int wm = wave >> 1, wn = wave & 1;

    const int nwg = gridDim.x;
    const int o   = blockIdx.x;
    const int swz = (o & 7) * (nwg >> 3) + (o >> 3);
    const int bn  = (swz & 7) * 128;          // gx = 1024/128 = 8
    const int bm  = (swz >> 3) * 128;

    const int c0 = wave * 128 + lane;
    const int rS = c0 >> 2;
    const int kS = (c0 & 3) * 8;
    const u16* srcA0 = A  + (size_t)(bm + rS) * DFF_ + kS;
    const u16* srcA1 = srcA0 + (size_t)16 * DFF_;
    const u16* srcB0 = Bm + (size_t)(bn + rS) * DFF_ + kS;
    const u16* srcB1 = srcB0 + (size_t)16 * DFF_;
    u16* dstA0 = &As[0][0] + wave * 1024;
    u16* dstA1 = dstA0 + 512;
    u16* dstB0 = &Bs[0][0] + wave * 1024;
    u16* dstB1 = dstB0 + 512;

    const int fr = lane & 15;
    const int kq = (lane >> 4) * 8;
    const u16* apA = &As[wm * 64 + fr][0] + kq;
    const u16* apB = &Bs[wn * 64 + fr][0] + kq;

    f32x4 acc[4][4];
    #pragma unroll
    for (int i = 0; i < 4; ++i)
        #pragma unroll
        for (int j = 0; j < 4; ++j)
            acc[i][j] = (f32x4)0.0f;

    for (int k0 = 0; k0 < DFF_; k0 += 32) {
        gload_lds16(srcA0 + k0, dstA0);
        gload_lds16(srcA1 + k0, dstA1);
        gload_lds16(srcB0 + k0, dstB0);
        gload_lds16(srcB1 + k0, dstB1);
        __syncthreads();
        bf16x8 af[4], bfv[4];
        #pragma unroll
        for (int i = 0; i < 4; ++i) {
            af[i]  = *(const bf16x8*)(apA + i * 512);
            bfv[i] = *(const bf16x8*)(apB + i * 512);
        }
        #pragma unroll
        for (int mi = 0; mi < 4; ++mi)
            #pragma unroll
            for (int ni = 0; ni < 4; ++ni)
                acc[mi][ni] = __builtin_amdgcn_mfma_f32_16x16x32_bf16(
                    af[mi], bfv[ni], acc[mi][ni], 0, 0, 0);
        __syncthreads();
    }

    const int mB = bm + wm * 64;
    const int nB = bn + wn * 64;
    const int rq = (lane >> 4) * 4;
    #pragma unroll
    for (int ni = 0; ni < 4; ++ni) {
        const int col = nB + ni * 16 + fr;
        const float bc = bias[col];
        #pragma unroll
        for (int mi = 0; mi < 4; ++mi) {
            const int rbase = mB + mi * 16 + rq;
            f32x4 v = acc[mi][ni];
            #pragma unroll
            for (int r = 0; r < 4; ++r) {
                int grow = row0 + rbase + r;
                int bb = grow >> 11;
                int tok = idxg[grow];
                outp[((size_t)bb * L_ + (size_t)tok) * D_ + col] = v[r] + bc;
            }
        }
    }
}

extern "C" void kernel_launch(void* const* d_in, const int* in_sizes, int n_in,
                              void* d_out, int out_size, void* d_ws, size_t ws_size,
                              hipStream_t stream)
{
    const float* x  = (const float*)d_in[0];
    const float* W1 = (const float*)d_in[1];
    const float* b1 = (const float*)d_in[2];
    const float* W2 = (const float*)d_in[3];
    const float* b2 = (const float*)d_in[4];
    const float* wr = (const float*)d_in[5];
    const float* br = (const float*)d_in[6];
    float* out = (float*)d_out;

    char* ws = (char*)d_ws;
    int*   idx    = (int*)ws;                          // 32 KB
    float* scores = (float*)(ws + (32 << 10));         // 64 KB
    int*   sel    = (int*)(ws + (96 << 10));           // 64 KB
    u16* W1T = (u16*)(ws + (256 << 10));               // [4096][1024] bf16, 8 MB
    u16* W2T = W1T + (size_t)DFF_ * D_;                // [1024][4096] bf16, 8 MB

    size_t fixedB = (size_t)(256 << 10) + (size_t)DFF_ * D_ * 2 * 2;
    size_t avail  = ws_size > fixedB ? ws_size - fixedB : 0;
    int RC = (int)(avail / (size_t)(D_ * 2 + DFF_ * 2));
    RC = (RC / 256) * 256;
    if (RC > B_ * K_) RC = B_ * K_;
    if (RC < 256) RC = 256;
    u16* xsel = (u16*)(ws + fixedB);                   // [RC][1024] bf16
    u16* hbuf = xsel + (size_t)RC * D_;                // [RC][4096] bf16

    prep_kernel<<<dim3(12288), 256, 0, stream>>>(x, wr, br, scores, W1, W2, W1T, W2T);
    rank_zero_kernel<<<dim3(16, 4), 256, 0, stream>>>(scores, sel, out);
    compact_kernel<<<dim3(B_), 256, 0, stream>>>(sel, idx);

    for (int r0 = 0; r0 < B_ * K_; r0 += RC) {
        int rc = (B_ * K_ - r0 < RC) ? (B_ * K_ - r0) : RC;
        gather_bf16_kernel<<<dim3(rc), 256, 0, stream>>>(x, idx, r0, xsel);
        gemm1_8ph_kernel<<<dim3((DFF_ / 256) * (rc / 256)), 512, 0, stream>>>(
            xsel, W1T, b1, hbuf);
        gemm2_kernel<<<dim3((D_ / 128) * (rc / 128)), 256, 0, stream>>>(
            hbuf, W2T, b2, out, idx, r0);
    }
}

// Round 5
// 300.694 us; speedup vs baseline: 1.4037x; 1.4037x over previous
//
#include <hip/hip_runtime.h>
#include <hip/hip_bf16.h>

#define B_   4
#define L_   4096
#define D_   1024
#define DFF_ 4096
#define K_   2048

typedef __attribute__((ext_vector_type(8))) short bf16x8;
typedef __attribute__((ext_vector_type(4))) float f32x4;
typedef unsigned short u16;

__device__ __forceinline__ u16 f2bf(float f) {
    unsigned u = __float_as_uint(f);
    u += 0x7fffu + ((u >> 16) & 1u);          // round-to-nearest-even
    return (u16)(u >> 16);
}

__device__ __forceinline__ float gelu_fast(float v) {
    float z = 1.5957691216057308f * v * (1.0f + 0.044715f * v * v);
    float e = __builtin_amdgcn_exp2f(-1.4426950408889634f * z);
    return v * __builtin_amdgcn_rcpf(1.0f + e);
}

__device__ __forceinline__ void gload_lds16(const void* g, void* l) {
    __builtin_amdgcn_global_load_lds(
        (const __attribute__((address_space(1))) void*)g,
        (__attribute__((address_space(3))) void*)l, 16, 0, 0);
}

template<int N> __device__ __forceinline__ void wait_vm() {
    if constexpr (N == 0) asm volatile("s_waitcnt vmcnt(0)" ::: "memory");
    else if constexpr (N == 3) asm volatile("s_waitcnt vmcnt(3)" ::: "memory");
    else if constexpr (N == 4) asm volatile("s_waitcnt vmcnt(4)" ::: "memory");
    __builtin_amdgcn_sched_barrier(0);
}

// ============ fused prep: score (blocks 0..4095) + W1 transpose (4096..8191)
// ============             + W2 transpose (8192..12287)
__global__ __launch_bounds__(256) void prep_kernel(
    const float* __restrict__ x, const float* __restrict__ wr,
    const float* __restrict__ br, float* __restrict__ scores,
    const float* __restrict__ W1, const float* __restrict__ W2,
    u16* __restrict__ W1T, u16* __restrict__ W2T)
{
    __shared__ float t[32][33];
    const int bb = blockIdx.x;
    if (bb < 4096) {
        int gtid  = bb * 256 + threadIdx.x;
        int token = gtid >> 6;
        int lane  = threadIdx.x & 63;
        const float* xr = x + (size_t)token * D_;
        double acc = 0.0;
        #pragma unroll
        for (int i = 0; i < 4; ++i) {
            int off = (lane + i * 64) * 4;
            float4 xv = *(const float4*)(xr + off);
            float4 wv = *(const float4*)(wr + off);
            acc += (double)xv.x * wv.x + (double)xv.y * wv.y +
                   (double)xv.z * wv.z + (double)xv.w * wv.w;
        }
        #pragma unroll
        for (int off = 32; off > 0; off >>= 1)
            acc += __shfl_down(acc, off);
        if (lane == 0) scores[token] = (float)(acc + (double)br[0]);
        return;
    }
    const float* in; u16* outb; int RK, RN, bx, by;
    if (bb < 8192) {
        int i = bb - 4096; in = W1; outb = W1T; RK = D_; RN = DFF_;
        bx = i & 127; by = i >> 7;
    } else {
        int i = bb - 8192; in = W2; outb = W2T; RK = DFF_; RN = D_;
        bx = i & 31; by = i >> 5;
    }
    int n0 = bx * 32, k0 = by * 32;
    int tx = threadIdx.x & 31, ty = threadIdx.x >> 5;
    #pragma unroll
    for (int i = 0; i < 4; ++i)
        t[ty + 8 * i][tx] = in[(size_t)(k0 + ty + 8 * i) * RN + (n0 + tx)];
    __syncthreads();
    #pragma unroll
    for (int i = 0; i < 4; ++i)
        outb[(size_t)(n0 + ty + 8 * i) * RK + (k0 + tx)] = f2bf(t[tx][ty + 8 * i]);
}

// ============ rank (exact top-k, jax tie-break) + zero unselected out rows
__global__ __launch_bounds__(256) void rank_zero_kernel(
    const float* __restrict__ scores, int* __restrict__ sel,
    float* __restrict__ out)
{
    __shared__ float sc[L_];
    __shared__ int selLds[256];
    int b = blockIdx.y;
    int t = threadIdx.x;
    int l = blockIdx.x * 256 + t;
    const float* sb = scores + b * L_;
    for (int i = t; i < L_; i += 256) sc[i] = sb[i];
    __syncthreads();
    float s = sc[l];
    int cnt = 0;
    for (int j = 0; j < L_; ++j) {
        float v = sc[j];
        cnt += (int)((v > s) || (v == s && j < l));
    }
    int issel = (cnt < K_) ? 1 : 0;
    sel[b * L_ + l] = issel;
    selLds[t] = issel;
    __syncthreads();
    float* obase = out + ((size_t)b * L_ + (size_t)blockIdx.x * 256) * D_;
    float4 z = make_float4(0.f, 0.f, 0.f, 0.f);
    for (int j = 0; j < 256; ++j)
        if (!selLds[j])
            *(float4*)(obase + (size_t)j * D_ + t * 4) = z;
}

// ---------------- compact selected indices (ascending) ----------------
__global__ __launch_bounds__(256) void compact_kernel(
    const int* __restrict__ sel, int* __restrict__ idx)
{
    __shared__ int psum[256];
    int b = blockIdx.x, t = threadIdx.x;
    const int* sb = sel + b * L_;
    int base = t * 16;
    int flags[16]; int c = 0;
    #pragma unroll
    for (int i = 0; i < 16; ++i) { flags[i] = sb[base + i]; c += flags[i]; }
    psum[t] = c;
    __syncthreads();
    if (t == 0) {
        int acc = 0;
        for (int j = 0; j < 256; ++j) { int v = psum[j]; psum[j] = acc; acc += v; }
    }
    __syncthreads();
    int p = psum[t];
    #pragma unroll
    for (int i = 0; i < 16; ++i)
        if (flags[i]) idx[b * K_ + (p++)] = base + i;
}

// ---------------- gather selected rows, fp32->bf16 ----------------
__global__ __launch_bounds__(256) void gather_bf16_kernel(
    const float* __restrict__ x, const int* __restrict__ idxg,
    int row0, u16* __restrict__ xsel)
{
    int rl = blockIdx.x;
    int grow = row0 + rl;
    int tok = idxg[grow];
    int bb = grow >> 11;
    const float* src = x + ((size_t)bb * L_ + (size_t)tok) * D_;
    int t = threadIdx.x;
    float4 v = *(const float4*)(src + t * 4);
    ushort4 o;
    o.x = f2bf(v.x); o.y = f2bf(v.y); o.z = f2bf(v.z); o.w = f2bf(v.w);
    *(ushort4*)(xsel + (size_t)rl * D_ + t * 4) = o;
}

// ======================= unified 8-phase MFMA GEMM (T3+T4+T5) =======================
// BN = 256 fixed. 8 waves (2M x 4N). A: [M][KD] bf16. Bm: [N][KD] bf16 (n-major).
// EPI 0 (gemm1): h = bf16(gelu(acc+bias)) via LDS C-tile repack, coalesced stores.
// EPI 1 (gemm2): out[b][tok][col] = acc + bias  (fp32 scatter).
template<int BM, int KD, int EPI>
__global__ __launch_bounds__(512, 2) void gemm_8ph_kernel(
    const u16* __restrict__ A, const u16* __restrict__ Bm,
    const float* __restrict__ bias, u16* __restrict__ hout,
    float* __restrict__ outp, const int* __restrict__ idxg, int row0)
{
    constexpr int BN     = 256;
    constexpr int NT     = KD / 64;           // K-tiles
    constexpr int M_REP  = BM / 32;           // m-fragments per wave
    constexpr int M_HALF = BM / 64;           // m-fragments per phase
    constexpr int IFL    = BM / 128 + 2;      // loads in flight at K-tile boundary

    // LDS: 4 A-slots of [BM][32] + 4 B-slots of [256][32] (slot = d*2+h).
    // For EPI 0 (BM=256) the whole 128 KiB is reused as the 256x256 bf16 C-tile.
    __shared__ u16 SH[(BM + BN) * 128];
    u16* SA = SH;
    u16* SB = SH + BM * 128;

    const int tid  = threadIdx.x;
    const int lane = tid & 63;
    const int wid  = tid >> 6;
    const int wm = wid >> 2, wn = wid & 3;
    const int fr = lane & 15;
    const int kq = (lane >> 4) * 8;
    const int rq = (lane >> 4) * 4;

    // XCD-aware swizzle (nwg always % 8 == 0 here)
    constexpr int gx = (EPI == 0 ? DFF_ : D_) / 256;
    const int nwg = gridDim.x;
    const int o   = blockIdx.x;
    const int swz = (o & 7) * (nwg >> 3) + (o >> 3);
    const int bn  = (swz % gx) * 256;
    const int bm  = (swz / gx) * BM;

    // staging invariants: thread tid -> row tid>>2, k-col (tid&3)*8 (16B chunk)
    const int srow = tid >> 2;
    const int skof = (tid & 3) * 8;
    const u16* Abase = A  + (size_t)(bm + srow) * KD + skof;
    const u16* Bbase = Bm + (size_t)(bn + srow) * KD + skof;

    f32x4 acc[M_REP][4];
    #pragma unroll
    for (int m = 0; m < M_REP; ++m)
        #pragma unroll
        for (int n = 0; n < 4; ++n) acc[m][n] = (f32x4)0.0f;

    // stage half-tile s: kt=s>>2, j=s&3 {0:Ak0,1:Bk0,2:Ak1,3:Bk1}
    auto stage = [&](int s) {
        int kt = s >> 2, j = s & 3;
        int d = kt & 1, h = j >> 1;
        int koff = kt * 64 + h * 32;
        if (j & 1) {
            u16* dst = SB + (d * 2 + h) * (BN * 32) + tid * 8;
            gload_lds16(Bbase + koff, dst);
            gload_lds16(Bbase + koff + (size_t)128 * KD, dst + 4096);
        } else {
            u16* dst = SA + (d * 2 + h) * (BM * 32) + tid * 8;
            gload_lds16(Abase + koff, dst);
            if constexpr (BM == 256)
                gload_lds16(Abase + koff + (size_t)128 * KD, dst + 4096);
        }
    };

    // prologue: stage halves 0..5 (K-tile0 full + K-tile1 k0-halves)
    #pragma unroll
    for (int s = 0; s < 6; ++s) stage(s);
    wait_vm<IFL>();                            // kt0's halves complete
    __builtin_amdgcn_s_barrier();

    bf16x8 bfv[4];
    for (int i = 0; i < NT / 2; ++i) {
        #pragma unroll
        for (int p = 0; p < 8; ++p) {
            const int d   = (2 * i + (p >> 2)) & 1;
            const int kh  = (p >> 1) & 1;
            const int mlo = (p & 1) * M_HALF;
            if ((p & 1) == 0) {
                #pragma unroll
                for (int n = 0; n < 4; ++n)
                    bfv[n] = *(const bf16x8*)(SB + (d * 2 + kh) * (BN * 32) +
                              (wn * 64 + n * 16 + fr) * 32 + kq);
            }
            bf16x8 af[M_HALF];
            #pragma unroll
            for (int q = 0; q < M_HALF; ++q)
                af[q] = *(const bf16x8*)(SA + (d * 2 + kh) * (BM * 32) +
                          (wm * (BM / 2) + (mlo + q) * 16 + fr) * 32 + kq);
            // stage one half-tile, 6 ahead (every overwrite >= 1 barrier after last read)
            int s = 8 * i + p + 6;
            if (s < 4 * NT) stage(s);
            __builtin_amdgcn_s_barrier();
            asm volatile("s_waitcnt lgkmcnt(0)" ::: "memory");
            __builtin_amdgcn_sched_barrier(0);
            __builtin_amdgcn_s_setprio(1);
            #pragma unroll
            for (int q = 0; q < M_HALF; ++q)
                #pragma unroll
                for (int n = 0; n < 4; ++n)
                    acc[mlo + q][n] = __builtin_amdgcn_mfma_f32_16x16x32_bf16(
                        af[q], bfv[n], acc[mlo + q][n], 0, 0, 0);
            __builtin_amdgcn_s_setprio(0);
            // K-tile boundary: counted vmcnt; drain to 0 only entering last tile
            if (p == 3) {
                if (i == NT / 2 - 1) wait_vm<0>(); else wait_vm<IFL>();
            } else if (p == 7) {
                if (i < NT / 2 - 1) wait_vm<IFL>();
            }
            __builtin_amdgcn_s_barrier();
        }
    }

    if constexpr (EPI == 0) {
        // bias+gelu -> bf16 LDS C-tile (bank-XOR'd), then per-instruction-coalesced stores
        u16* ct = SH;                          // [256][256] bf16 = 128 KiB
        #pragma unroll
        for (int n = 0; n < 4; ++n) {
            const int col = wn * 64 + n * 16 + fr;
            const float bc = bias[bn + col];
            #pragma unroll
            for (int m = 0; m < M_REP; ++m) {
                const int rb = wm * (BM / 2) + m * 16 + rq;
                #pragma unroll
                for (int r = 0; r < 4; ++r) {
                    int row = rb + r;
                    int pc  = col ^ (((row >> 2) & 3) << 4);   // bank spread
                    ct[row * 256 + pc] = f2bf(gelu_fast(acc[m][n][r] + bc));
                }
            }
        }
        __syncthreads();
        const int chunk = tid & 31;            // 16B chunk within a row
        const int rw    = tid >> 5;            // 0..15
        #pragma unroll
        for (int pass = 0; pass < 16; ++pass) {
            int row = pass * 16 + rw;
            int pb  = (chunk * 8) ^ (((row >> 2) & 3) << 4);
            bf16x8 v = *(const bf16x8*)(ct + row * 256 + pb);
            // half-wave writes 512 contiguous B -> full 64B lines, no RMW
            *(bf16x8*)(hout + (size_t)(bm + row) * DFF_ + bn + chunk * 8) = v;
        }
    } else {
        // fp32 scatter: 16-lane groups store 64B contiguous -> full lines
        #pragma unroll
        for (int n = 0; n < 4; ++n) {
            const int col = bn + wn * 64 + n * 16 + fr;
            const float bc = bias[col];
            #pragma unroll
            for (int m = 0; m < M_REP; ++m) {
                const int rbase = bm + wm * (BM / 2) + m * 16 + rq;
                #pragma unroll
                for (int r = 0; r < 4; ++r) {
                    int grow = row0 + rbase + r;
                    int bb = grow >> 11;
                    int tok = idxg[grow];
                    outp[((size_t)bb * L_ + (size_t)tok) * D_ + col] =
                        acc[m][n][r] + bc;
                }
            }
        }
    }
}

extern "C" void kernel_launch(void* const* d_in, const int* in_sizes, int n_in,
                              void* d_out, int out_size, void* d_ws, size_t ws_size,
                              hipStream_t stream)
{
    const float* x  = (const float*)d_in[0];
    const float* W1 = (const float*)d_in[1];
    const float* b1 = (const float*)d_in[2];
    const float* W2 = (const float*)d_in[3];
    const float* b2 = (const float*)d_in[4];
    const float* wr = (const float*)d_in[5];
    const float* br = (const float*)d_in[6];
    float* out = (float*)d_out;

    char* ws = (char*)d_ws;
    int*   idx    = (int*)ws;                          // 32 KB
    float* scores = (float*)(ws + (32 << 10));         // 64 KB
    int*   sel    = (int*)(ws + (96 << 10));           // 64 KB
    u16* W1T = (u16*)(ws + (256 << 10));               // [4096][1024] bf16, 8 MB
    u16* W2T = W1T + (size_t)DFF_ * D_;                // [1024][4096] bf16, 8 MB

    size_t fixedB = (size_t)(256 << 10) + (size_t)DFF_ * D_ * 2 * 2;
    size_t avail  = ws_size > fixedB ? ws_size - fixedB : 0;
    int RC = (int)(avail / (size_t)(D_ * 2 + DFF_ * 2));
    RC = (RC / 256) * 256;
    if (RC > B_ * K_) RC = B_ * K_;
    if (RC < 256) RC = 256;
    u16* xsel = (u16*)(ws + fixedB);                   // [RC][1024] bf16
    u16* hbuf = xsel + (size_t)RC * D_;                // [RC][4096] bf16

    prep_kernel<<<dim3(12288), 256, 0, stream>>>(x, wr, br, scores, W1, W2, W1T, W2T);
    rank_zero_kernel<<<dim3(16, 4), 256, 0, stream>>>(scores, sel, out);
    compact_kernel<<<dim3(B_), 256, 0, stream>>>(sel, idx);

    for (int r0 = 0; r0 < B_ * K_; r0 += RC) {
        int rc = (B_ * K_ - r0 < RC) ? (B_ * K_ - r0) : RC;
        gather_bf16_kernel<<<dim3(rc), 256, 0, stream>>>(x, idx, r0, xsel);
        gemm_8ph_kernel<256, D_, 0><<<dim3((DFF_ / 256) * (rc / 256)), 512, 0, stream>>>(
            xsel, W1T, b1, hbuf, nullptr, nullptr, 0);
        gemm_8ph_kernel<128, DFF_, 1><<<dim3((D_ / 256) * (rc / 128)), 512, 0, stream>>>(
            hbuf, W2T, b2, nullptr, out, idx, r0);
    }
}

// Round 6
// 221.464 us; speedup vs baseline: 1.9059x; 1.3578x over previous
//
#include <hip/hip_runtime.h>
#include <hip/hip_bf16.h>

#define B_   4
#define L_   4096
#define D_   1024
#define DFF_ 4096
#define K_   2048

typedef __attribute__((ext_vector_type(8))) short bf16x8;
typedef __attribute__((ext_vector_type(4))) float f32x4;
typedef unsigned short u16;

__device__ __forceinline__ u16 f2bf(float f) {
    unsigned u = __float_as_uint(f);
    u += 0x7fffu + ((u >> 16) & 1u);          // round-to-nearest-even
    return (u16)(u >> 16);
}

__device__ __forceinline__ float gelu_fast(float v) {
    float z = 1.5957691216057308f * v * (1.0f + 0.044715f * v * v);
    float e = __builtin_amdgcn_exp2f(-1.4426950408889634f * z);
    return v * __builtin_amdgcn_rcpf(1.0f + e);
}

__device__ __forceinline__ void gload_lds16(const void* g, void* l) {
    __builtin_amdgcn_global_load_lds(
        (const __attribute__((address_space(1))) void*)g,
        (__attribute__((address_space(3))) void*)l, 16, 0, 0);
}

template<int N> __device__ __forceinline__ void wait_vm() {
    if constexpr (N == 0) asm volatile("s_waitcnt vmcnt(0)" ::: "memory");
    else if constexpr (N == 3) asm volatile("s_waitcnt vmcnt(3)" ::: "memory");
    else if constexpr (N == 4) asm volatile("s_waitcnt vmcnt(4)" ::: "memory");
    __builtin_amdgcn_sched_barrier(0);
}

// ============ fused prep: score (blocks 0..4095) + W1 transpose (4096..8191)
// ============             + W2 transpose (8192..12287)
__global__ __launch_bounds__(256) void prep_kernel(
    const float* __restrict__ x, const float* __restrict__ wr,
    const float* __restrict__ br, float* __restrict__ scores,
    const float* __restrict__ W1, const float* __restrict__ W2,
    u16* __restrict__ W1T, u16* __restrict__ W2T)
{
    __shared__ float t[32][33];
    const int bb = blockIdx.x;
    if (bb < 4096) {
        int gtid  = bb * 256 + threadIdx.x;
        int token = gtid >> 6;
        int lane  = threadIdx.x & 63;
        const float* xr = x + (size_t)token * D_;
        double acc = 0.0;
        #pragma unroll
        for (int i = 0; i < 4; ++i) {
            int off = (lane + i * 64) * 4;
            float4 xv = *(const float4*)(xr + off);
            float4 wv = *(const float4*)(wr + off);
            acc += (double)xv.x * wv.x + (double)xv.y * wv.y +
                   (double)xv.z * wv.z + (double)xv.w * wv.w;
        }
        #pragma unroll
        for (int off = 32; off > 0; off >>= 1)
            acc += __shfl_down(acc, off);
        if (lane == 0) scores[token] = (float)(acc + (double)br[0]);
        return;
    }
    const float* in; u16* outb; int RK, RN, bx, by;
    if (bb < 8192) {
        int i = bb - 4096; in = W1; outb = W1T; RK = D_; RN = DFF_;
        bx = i & 127; by = i >> 7;
    } else {
        int i = bb - 8192; in = W2; outb = W2T; RK = DFF_; RN = D_;
        bx = i & 31; by = i >> 5;
    }
    int n0 = bx * 32, k0 = by * 32;
    int tx = threadIdx.x & 31, ty = threadIdx.x >> 5;
    #pragma unroll
    for (int i = 0; i < 4; ++i)
        t[ty + 8 * i][tx] = in[(size_t)(k0 + ty + 8 * i) * RN + (n0 + tx)];
    __syncthreads();
    #pragma unroll
    for (int i = 0; i < 4; ++i)
        outb[(size_t)(n0 + ty + 8 * i) * RK + (k0 + tx)] = f2bf(t[tx][ty + 8 * i]);
}

// ============ rank (exact top-k, jax tie-break) + zero unselected out rows
// grid (L_/64, B_): 64 tokens/block, 4 threads/token each scanning 1024 scores.
__global__ __launch_bounds__(256) void rank_zero_kernel(
    const float* __restrict__ scores, int* __restrict__ sel,
    float* __restrict__ out)
{
    __shared__ float sc[L_];
    __shared__ int selLds[64];
    const int b = blockIdx.y;
    const int t = threadIdx.x;
    const float* sb = scores + b * L_;
    for (int i = t; i < L_; i += 256) sc[i] = sb[i];
    __syncthreads();
    const int tg  = t >> 2;                    // token within block
    const int sub = t & 3;                     // quarter of the scan
    const int l   = blockIdx.x * 64 + tg;
    const float s = sc[l];
    int cnt = 0;
    const float4* sc4 = (const float4*)sc;
    const int base4 = sub * 256;
    for (int j4 = 0; j4 < 256; ++j4) {
        float4 v = sc4[base4 + j4];
        int j = (base4 + j4) * 4;
        cnt += (int)((v.x > s) || (v.x == s && (j + 0) < l));
        cnt += (int)((v.y > s) || (v.y == s && (j + 1) < l));
        cnt += (int)((v.z > s) || (v.z == s && (j + 2) < l));
        cnt += (int)((v.w > s) || (v.w == s && (j + 3) < l));
    }
    cnt += __shfl_xor(cnt, 1);
    cnt += __shfl_xor(cnt, 2);
    const int issel = (cnt < K_) ? 1 : 0;
    if (sub == 0) { sel[b * L_ + l] = issel; selLds[tg] = issel; }
    __syncthreads();
    // zero the unselected rows among this block's 64 tokens
    float* obase = out + ((size_t)b * L_ + (size_t)blockIdx.x * 64) * D_;
    const float4 z = make_float4(0.f, 0.f, 0.f, 0.f);
    for (int r = 0; r < 64; ++r)
        if (!selLds[r])
            *(float4*)(obase + (size_t)r * D_ + t * 4) = z;
}

// ---------------- compact selected indices (ascending) ----------------
__global__ __launch_bounds__(256) void compact_kernel(
    const int* __restrict__ sel, int* __restrict__ idx)
{
    __shared__ int psum[256];
    int b = blockIdx.x, t = threadIdx.x;
    const int* sb = sel + b * L_;
    int base = t * 16;
    int flags[16]; int c = 0;
    #pragma unroll
    for (int i = 0; i < 16; ++i) { flags[i] = sb[base + i]; c += flags[i]; }
    psum[t] = c;
    __syncthreads();
    if (t == 0) {
        int acc = 0;
        for (int j = 0; j < 256; ++j) { int v = psum[j]; psum[j] = acc; acc += v; }
    }
    __syncthreads();
    int p = psum[t];
    #pragma unroll
    for (int i = 0; i < 16; ++i)
        if (flags[i]) idx[b * K_ + (p++)] = base + i;
}

// ---------------- gather selected rows, fp32->bf16 ----------------
__global__ __launch_bounds__(256) void gather_bf16_kernel(
    const float* __restrict__ x, const int* __restrict__ idxg,
    int row0, u16* __restrict__ xsel)
{
    int rl = blockIdx.x;
    int grow = row0 + rl;
    int tok = idxg[grow];
    int bb = grow >> 11;
    const float* src = x + ((size_t)bb * L_ + (size_t)tok) * D_;
    int t = threadIdx.x;
    float4 v = *(const float4*)(src + t * 4);
    ushort4 o;
    o.x = f2bf(v.x); o.y = f2bf(v.y); o.z = f2bf(v.z); o.w = f2bf(v.w);
    *(ushort4*)(xsel + (size_t)rl * D_ + t * 4) = o;
}

// ======================= unified 8-phase MFMA GEMM (T3+T4+T5) =======================
// BN = 256 fixed. 8 waves (2M x 4N). A: [M][KD] bf16. Bm: [N][KD] bf16 (n-major).
// EPI 0 (gemm1): h = bf16(gelu(acc+bias)) via LDS C-tile repack, coalesced stores.
// EPI 1 (gemm2): out[b][tok][col] = acc + bias  (fp32 scatter).
template<int BM, int KD, int EPI>
__global__ __launch_bounds__(512, 2) void gemm_8ph_kernel(
    const u16* __restrict__ A, const u16* __restrict__ Bm,
    const float* __restrict__ bias, u16* __restrict__ hout,
    float* __restrict__ outp, const int* __restrict__ idxg, int row0)
{
    constexpr int BN     = 256;
    constexpr int NT     = KD / 64;           // K-tiles
    constexpr int M_REP  = BM / 32;           // m-fragments per wave
    constexpr int M_HALF = BM / 64;           // m-fragments per phase
    constexpr int IFL    = BM / 128 + 2;      // loads in flight at K-tile boundary

    __shared__ u16 SH[(BM + BN) * 128];
    u16* SA = SH;
    u16* SB = SH + BM * 128;

    const int tid  = threadIdx.x;
    const int lane = tid & 63;
    const int wid  = tid >> 6;
    const int wm = wid >> 2, wn = wid & 3;
    const int fr = lane & 15;
    const int kq = (lane >> 4) * 8;
    const int rq = (lane >> 4) * 4;

    constexpr int gx = (EPI == 0 ? DFF_ : D_) / 256;
    const int nwg = gridDim.x;
    const int o   = blockIdx.x;
    const int swz = (o & 7) * (nwg >> 3) + (o >> 3);
    const int bn  = (swz % gx) * 256;
    const int bm  = (swz / gx) * BM;

    const int srow = tid >> 2;
    const int skof = (tid & 3) * 8;
    const u16* Abase = A  + (size_t)(bm + srow) * KD + skof;
    const u16* Bbase = Bm + (size_t)(bn + srow) * KD + skof;

    f32x4 acc[M_REP][4];
    #pragma unroll
    for (int m = 0; m < M_REP; ++m)
        #pragma unroll
        for (int n = 0; n < 4; ++n) acc[m][n] = (f32x4)0.0f;

    auto stage = [&](int s) {
        int kt = s >> 2, j = s & 3;
        int d = kt & 1, h = j >> 1;
        int koff = kt * 64 + h * 32;
        if (j & 1) {
            u16* dst = SB + (d * 2 + h) * (BN * 32) + tid * 8;
            gload_lds16(Bbase + koff, dst);
            gload_lds16(Bbase + koff + (size_t)128 * KD, dst + 4096);
        } else {
            u16* dst = SA + (d * 2 + h) * (BM * 32) + tid * 8;
            gload_lds16(Abase + koff, dst);
            if constexpr (BM == 256)
                gload_lds16(Abase + koff + (size_t)128 * KD, dst + 4096);
        }
    };

    #pragma unroll
    for (int s = 0; s < 6; ++s) stage(s);
    wait_vm<IFL>();
    __builtin_amdgcn_s_barrier();

    bf16x8 bfv[4];
    for (int i = 0; i < NT / 2; ++i) {
        #pragma unroll
        for (int p = 0; p < 8; ++p) {
            const int d   = (2 * i + (p >> 2)) & 1;
            const int kh  = (p >> 1) & 1;
            const int mlo = (p & 1) * M_HALF;
            if ((p & 1) == 0) {
                #pragma unroll
                for (int n = 0; n < 4; ++n)
                    bfv[n] = *(const bf16x8*)(SB + (d * 2 + kh) * (BN * 32) +
                              (wn * 64 + n * 16 + fr) * 32 + kq);
            }
            bf16x8 af[M_HALF];
            #pragma unroll
            for (int q = 0; q < M_HALF; ++q)
                af[q] = *(const bf16x8*)(SA + (d * 2 + kh) * (BM * 32) +
                          (wm * (BM / 2) + (mlo + q) * 16 + fr) * 32 + kq);
            int s = 8 * i + p + 6;
            if (s < 4 * NT) stage(s);
            __builtin_amdgcn_s_barrier();
            asm volatile("s_waitcnt lgkmcnt(0)" ::: "memory");
            __builtin_amdgcn_sched_barrier(0);
            __builtin_amdgcn_s_setprio(1);
            #pragma unroll
            for (int q = 0; q < M_HALF; ++q)
                #pragma unroll
                for (int n = 0; n < 4; ++n)
                    acc[mlo + q][n] = __builtin_amdgcn_mfma_f32_16x16x32_bf16(
                        af[q], bfv[n], acc[mlo + q][n], 0, 0, 0);
            __builtin_amdgcn_s_setprio(0);
            if (p == 3) {
                if (i == NT / 2 - 1) wait_vm<0>(); else wait_vm<IFL>();
            } else if (p == 7) {
                if (i < NT / 2 - 1) wait_vm<IFL>();
            }
            __builtin_amdgcn_s_barrier();
        }
    }

    if constexpr (EPI == 0) {
        u16* ct = SH;                          // [256][256] bf16 = 128 KiB
        #pragma unroll
        for (int n = 0; n < 4; ++n) {
            const int col = wn * 64 + n * 16 + fr;
            const float bc = bias[bn + col];
            #pragma unroll
            for (int m = 0; m < M_REP; ++m) {
                const int rb = wm * (BM / 2) + m * 16 + rq;
                #pragma unroll
                for (int r = 0; r < 4; ++r) {
                    int row = rb + r;
                    int pc  = col ^ (((row >> 2) & 3) << 4);   // bank spread
                    ct[row * 256 + pc] = f2bf(gelu_fast(acc[m][n][r] + bc));
                }
            }
        }
        __syncthreads();
        const int chunk = tid & 31;
        const int rw    = tid >> 5;
        #pragma unroll
        for (int pass = 0; pass < 16; ++pass) {
            int row = pass * 16 + rw;
            int pb  = (chunk * 8) ^ (((row >> 2) & 3) << 4);
            bf16x8 v = *(const bf16x8*)(ct + row * 256 + pb);
            *(bf16x8*)(hout + (size_t)(bm + row) * DFF_ + bn + chunk * 8) = v;
        }
    } else {
        #pragma unroll
        for (int n = 0; n < 4; ++n) {
            const int col = bn + wn * 64 + n * 16 + fr;
            const float bc = bias[col];
            #pragma unroll
            for (int m = 0; m < M_REP; ++m) {
                const int rbase = bm + wm * (BM / 2) + m * 16 + rq;
                #pragma unroll
                for (int r = 0; r < 4; ++r) {
                    int grow = row0 + rbase + r;
                    int bb = grow >> 11;
                    int tok = idxg[grow];
                    outp[((size_t)bb * L_ + (size_t)tok) * D_ + col] =
                        acc[m][n][r] + bc;
                }
            }
        }
    }
}

extern "C" void kernel_launch(void* const* d_in, const int* in_sizes, int n_in,
                              void* d_out, int out_size, void* d_ws, size_t ws_size,
                              hipStream_t stream)
{
    const float* x  = (const float*)d_in[0];
    const float* W1 = (const float*)d_in[1];
    const float* b1 = (const float*)d_in[2];
    const float* W2 = (const float*)d_in[3];
    const float* b2 = (const float*)d_in[4];
    const float* wr = (const float*)d_in[5];
    const float* br = (const float*)d_in[6];
    float* out = (float*)d_out;

    char* ws = (char*)d_ws;
    int*   idx    = (int*)ws;                          // 32 KB
    float* scores = (float*)(ws + (32 << 10));         // 64 KB
    int*   sel    = (int*)(ws + (96 << 10));           // 64 KB
    u16* W1T = (u16*)(ws + (256 << 10));               // [4096][1024] bf16, 8 MB
    u16* W2T = W1T + (size_t)DFF_ * D_;                // [1024][4096] bf16, 8 MB

    size_t fixedB = (size_t)(256 << 10) + (size_t)DFF_ * D_ * 2 * 2;
    size_t avail  = ws_size > fixedB ? ws_size - fixedB : 0;
    int RC = (int)(avail / (size_t)(D_ * 2 + DFF_ * 2));
    RC = (RC / 256) * 256;
    if (RC > B_ * K_) RC = B_ * K_;
    if (RC < 256) RC = 256;
    u16* xsel = (u16*)(ws + fixedB);                   // [RC][1024] bf16
    u16* hbuf = xsel + (size_t)RC * D_;                // [RC][4096] bf16

    prep_kernel<<<dim3(12288), 256, 0, stream>>>(x, wr, br, scores, W1, W2, W1T, W2T);
    rank_zero_kernel<<<dim3(L_ / 64, B_), 256, 0, stream>>>(scores, sel, out);
    compact_kernel<<<dim3(B_), 256, 0, stream>>>(sel, idx);

    for (int r0 = 0; r0 < B_ * K_; r0 += RC) {
        int rc = (B_ * K_ - r0 < RC) ? (B_ * K_ - r0) : RC;
        gather_bf16_kernel<<<dim3(rc), 256, 0, stream>>>(x, idx, r0, xsel);
        gemm_8ph_kernel<256, D_, 0><<<dim3((DFF_ / 256) * (rc / 256)), 512, 0, stream>>>(
            xsel, W1T, b1, hbuf, nullptr, nullptr, 0);
        gemm_8ph_kernel<128, DFF_, 1><<<dim3((D_ / 256) * (rc / 128)), 512, 0, stream>>>(
            hbuf, W2T, b2, nullptr, out, idx, r0);
    }
}